// Round 1
// baseline (266.208 us; speedup 1.0000x reference)
//
#include <hip/hip_runtime.h>
#include <math.h>

// Problem constants: x [B=512, C=1024, H=8, W=8] f32.
#define C_DIM 1024
#define HW 64          // 8*8
#define NTHREADS 512   // per block
#define C_PER 32       // channels per c-slice (C_DIM / (NTHREADS/16))

#define EPSV 1e-8f
#define TINYF 1.17549435e-38f

// jax.random.key(1) -> threefry key data (0, 1).
// Mode: 1 = jax_threefry_partitionable=True (modern JAX default),
//       0 = legacy split-iota mode. Flip if absmax lands ~[0.03, 0.5].
#define THREEFRY_PARTITIONABLE 1

__device__ __forceinline__ void threefry2x32_01(unsigned x0, unsigned x1,
                                                unsigned& o0, unsigned& o1) {
    const unsigned ks0 = 0u, ks1 = 1u, ks2 = 0x1BD11BDBu; // 0x1BD11BDA ^ 0 ^ 1
    x0 += ks0; x1 += ks1;
#define TF_R(r) { x0 += x1; x1 = (x1 << (r)) | (x1 >> (32 - (r))); x1 ^= x0; }
    TF_R(13) TF_R(15) TF_R(26) TF_R(6)
    x0 += ks1; x1 += ks2 + 1u;
    TF_R(17) TF_R(29) TF_R(16) TF_R(24)
    x0 += ks2; x1 += ks0 + 2u;
    TF_R(13) TF_R(15) TF_R(26) TF_R(6)
    x0 += ks0; x1 += ks1 + 3u;
    TF_R(17) TF_R(29) TF_R(16) TF_R(24)
    x0 += ks1; x1 += ks2 + 4u;
    TF_R(13) TF_R(15) TF_R(26) TF_R(6)
    x0 += ks2; x1 += ks0 + 5u;
#undef TF_R
    o0 = x0; o1 = x1;
}

// Random 32 bits for flat gumbel index n (total size 32768).
__device__ __forceinline__ unsigned jax_random_bits(unsigned n) {
#if THREEFRY_PARTITIONABLE
    // counter = 64-bit flat index: (hi=0, lo=n); output = o0 ^ o1
    unsigned o0, o1;
    threefry2x32_01(0u, n, o0, o1);
    return o0 ^ o1;
#else
    // legacy: iota split in half; pair i -> counts (i, i+16384); concat(out0, out1)
    unsigned o0, o1;
    if (n < 16384u) { threefry2x32_01(n, n + 16384u, o0, o1); return o0; }
    else            { threefry2x32_01(n - 16384u, n, o0, o1); return o1; }
#endif
}

__device__ __forceinline__ bool bad_val(float v) {
    // inf or nan (exponent all ones), or negative
    return ((__float_as_uint(v) & 0x7F800000u) == 0x7F800000u) || (v < 0.0f);
}

__global__ __launch_bounds__(NTHREADS) void sa_fused_kernel(
    const float* __restrict__ x,
    const float* __restrict__ w11,  // [1,1,3,3]
    const float* __restrict__ w5,   // [4,2,3,3]
    const float* __restrict__ b5,   // [4]
    const float* __restrict__ w6,   // [1,4,3,3]
    const float* __restrict__ b6,   // [1]
    float* __restrict__ out)
{
    const int b = blockIdx.x;
    const int t = threadIdx.x;
    const int hw4 = t & 15;   // which float4 of the 8x8 map
    const int cs  = t >> 4;   // c-slice 0..31

    const float4* __restrict__ xb = (const float4*)x + (size_t)b * (C_DIM * HW / 4);
    float4* __restrict__ ob = (float4*)out + (size_t)b * (C_DIM * HW / 4);

    __shared__ float4 red[NTHREADS];
    __shared__ float sm[64];       // channel max m[h*8+w]
    __shared__ float sg[64];       // gumbel noise per (window, j)
    __shared__ float sa16[16];     // out2a (pooled 4x4)
    __shared__ float sb16[16];     // out2b (after 3x3 conv)
    __shared__ float so2[64];      // out2 resized to 8x8
    __shared__ float shid[4 * 64]; // conv5 hidden, relu'd
    __shared__ float sgate[64];    // sigmoid gate

    // ---- Phase 1: channel max over C=1024, float4-vectorized over hw ----
    float4 pm = make_float4(-INFINITY, -INFINITY, -INFINITY, -INFINITY);
    const int c0 = cs * C_PER;
#pragma unroll 8
    for (int i = 0; i < C_PER; ++i) {
        float4 v = xb[(c0 + i) * 16 + hw4];
        pm.x = fmaxf(pm.x, v.x); pm.y = fmaxf(pm.y, v.y);
        pm.z = fmaxf(pm.z, v.z); pm.w = fmaxf(pm.w, v.w);
    }
    red[t] = pm;
    __syncthreads();
#pragma unroll
    for (int s = 16; s >= 1; s >>= 1) {
        if (cs < s) {
            float4 a = red[t];
            float4 o = red[t + s * 16];
            a.x = fmaxf(a.x, o.x); a.y = fmaxf(a.y, o.y);
            a.z = fmaxf(a.z, o.z); a.w = fmaxf(a.w, o.w);
            red[t] = a;
        }
        __syncthreads();
    }
    if (t < 16) {
        float4 a = red[t];
        sm[t * 4 + 0] = a.x; sm[t * 4 + 1] = a.y;
        sm[t * 4 + 2] = a.z; sm[t * 4 + 3] = a.w;
    }
    // ---- Gumbel noise: exact JAX threefry + uniform + gumbel ----
    if (t < 64) {
        unsigned n = (unsigned)(b * 64 + t);
        unsigned bits = jax_random_bits(n);
        float f = __uint_as_float(0x3F800000u | (bits >> 9)) - 1.0f; // [0, 1-2^-23]
        float u = f + TINYF;          // * (1 - tiny) folds to 1.0f in f32
        u = fmaxf(TINYF, u);
        sg[t] = -logf(-logf(u));
    }
    __syncthreads();

    // ---- Windows: categorical sample + max + mean pooling ----
    if (t < 16) {
        int h2 = t >> 2, w2 = t & 3;
        float win[4], winc[4];
#pragma unroll
        for (int j = 0; j < 4; ++j) {
            int hh = 2 * h2 + (j >> 1), ww = 2 * w2 + (j & 1);
            float v = sm[hh * 8 + ww];
            win[j] = v;
            winc[j] = bad_val(v) ? EPSV : v;
        }
        int idx = 0;
        float best = winc[0] + sg[t * 4 + 0];
#pragma unroll
        for (int j = 1; j < 4; ++j) {
            float s = winc[j] + sg[t * 4 + j];
            if (s > best) { best = s; idx = j; }  // strict >: first-max tiebreak
        }
        float mo2 = winc[idx];
        float mo3 = fmaxf(fmaxf(win[0], win[1]), fmaxf(win[2], win[3]));
        float ssum = ((win[0] + win[1]) + win[2]) + win[3];
        float ao4 = ssum * 0.25f;
        sa16[t] = 0.1f * mo2 + 0.6f * mo3 + 0.3f * ao4;
    }
    __syncthreads();

    // ---- 3x3 conv (1->1, SAME, no bias) on 4x4 ----
    if (t < 16) {
        int i = t >> 2, j = t & 3;
        float acc = 0.0f;
#pragma unroll
        for (int dy = -1; dy <= 1; ++dy) {
            int yy = i + dy;
            if (yy < 0 || yy > 3) continue;
#pragma unroll
            for (int dx = -1; dx <= 1; ++dx) {
                int xx = j + dx;
                if (xx < 0 || xx > 3) continue;
                acc += sa16[yy * 4 + xx] * w11[(dy + 1) * 3 + (dx + 1)];
            }
        }
        sb16[t] = acc;
    }
    __syncthreads();

    // ---- Bilinear resize 4x4 -> 8x8 (align_corners=False, edge clamp) ----
    if (t < 64) {
        int y = t >> 3, xx2 = t & 7;
        float sy = (y + 0.5f) * 0.5f - 0.5f;
        float sx = (xx2 + 0.5f) * 0.5f - 0.5f;
        float fy = fminf(fmaxf(sy, 0.0f), 3.0f);
        float fx = fminf(fmaxf(sx, 0.0f), 3.0f);
        int iy0 = (int)floorf(fy); int iy1 = min(iy0 + 1, 3); float ry = fy - (float)iy0;
        int ix0 = (int)floorf(fx); int ix1 = min(ix0 + 1, 3); float rx = fx - (float)ix0;
        float v00 = sb16[iy0 * 4 + ix0], v01 = sb16[iy0 * 4 + ix1];
        float v10 = sb16[iy1 * 4 + ix0], v11 = sb16[iy1 * 4 + ix1];
        float top = v00 * (1.0f - rx) + v01 * rx;
        float bot = v10 * (1.0f - rx) + v11 * rx;
        so2[t] = top * (1.0f - ry) + bot * ry;
    }
    __syncthreads();

    // ---- conv5: [2 -> 4] 3x3 SAME + bias + relu, on 8x8; ch0=m, ch1=out2 ----
    if (t < 64) {
        int y = t >> 3, x2 = t & 7;
        float a0 = b5[0], a1 = b5[1], a2 = b5[2], a3 = b5[3];
#pragma unroll
        for (int dy = -1; dy <= 1; ++dy) {
            int yy = y + dy;
            if (yy < 0 || yy > 7) continue;
#pragma unroll
            for (int dx = -1; dx <= 1; ++dx) {
                int xx = x2 + dx;
                if (xx < 0 || xx > 7) continue;
                float i0 = sm[yy * 8 + xx];
                float i1 = so2[yy * 8 + xx];
                int kk = (dy + 1) * 3 + (dx + 1);
                a0 += i0 * w5[0 * 18 + kk] + i1 * w5[0 * 18 + 9 + kk];
                a1 += i0 * w5[1 * 18 + kk] + i1 * w5[1 * 18 + 9 + kk];
                a2 += i0 * w5[2 * 18 + kk] + i1 * w5[2 * 18 + 9 + kk];
                a3 += i0 * w5[3 * 18 + kk] + i1 * w5[3 * 18 + 9 + kk];
            }
        }
        shid[0 * 64 + t] = fmaxf(a0, 0.0f);
        shid[1 * 64 + t] = fmaxf(a1, 0.0f);
        shid[2 * 64 + t] = fmaxf(a2, 0.0f);
        shid[3 * 64 + t] = fmaxf(a3, 0.0f);
    }
    __syncthreads();

    // ---- conv6: [4 -> 1] 3x3 SAME + bias + sigmoid ----
    if (t < 64) {
        int y = t >> 3, x2 = t & 7;
        float acc = b6[0];
#pragma unroll
        for (int dy = -1; dy <= 1; ++dy) {
            int yy = y + dy;
            if (yy < 0 || yy > 7) continue;
#pragma unroll
            for (int dx = -1; dx <= 1; ++dx) {
                int xx = x2 + dx;
                if (xx < 0 || xx > 7) continue;
                int kk = (dy + 1) * 3 + (dx + 1);
                int p = yy * 8 + xx;
                acc += shid[0 * 64 + p] * w6[0 + kk]
                     + shid[1 * 64 + p] * w6[9 + kk]
                     + shid[2 * 64 + p] * w6[18 + kk]
                     + shid[3 * 64 + p] * w6[27 + kk];
            }
        }
        sgate[t] = 1.0f / (1.0f + expf(-acc));
    }
    __syncthreads();

    // ---- Phase 2: out = relu(x * gate), re-read x (L3-resident) ----
    float4 g4;
    g4.x = sgate[hw4 * 4 + 0]; g4.y = sgate[hw4 * 4 + 1];
    g4.z = sgate[hw4 * 4 + 2]; g4.w = sgate[hw4 * 4 + 3];
#pragma unroll 8
    for (int i = 0; i < C_PER; ++i) {
        float4 v = xb[(c0 + i) * 16 + hw4];
        float4 o;
        o.x = fmaxf(v.x * g4.x, 0.0f);
        o.y = fmaxf(v.y * g4.y, 0.0f);
        o.z = fmaxf(v.z * g4.z, 0.0f);
        o.w = fmaxf(v.w * g4.w, 0.0f);
        ob[(c0 + i) * 16 + hw4] = o;
    }
}

extern "C" void kernel_launch(void* const* d_in, const int* in_sizes, int n_in,
                              void* d_out, int out_size, void* d_ws, size_t ws_size,
                              hipStream_t stream) {
    const float* x   = (const float*)d_in[0];
    const float* w11 = (const float*)d_in[1];
    const float* w5  = (const float*)d_in[2];
    const float* b5  = (const float*)d_in[3];
    const float* w6  = (const float*)d_in[4];
    const float* b6  = (const float*)d_in[5];
    float* out = (float*)d_out;

    int B = in_sizes[0] / (C_DIM * HW);  // 512
    sa_fused_kernel<<<dim3(B), dim3(NTHREADS), 0, stream>>>(x, w11, w5, b5, w6, b6, out);
}

// Round 2
// 259.775 us; speedup vs baseline: 1.0248x; 1.0248x over previous
//
#include <hip/hip_runtime.h>
#include <math.h>

// x [B=512, C=1024, H=8, W=8] f32. out same shape.
#define C_DIM 1024
#define HW 64
#define NT_A 512            // kernel A threads
#define NT_B 256            // kernel B threads
#define F4_PER_BATCH 16384  // C_DIM*HW/4
#define EPSV 1e-8f
#define TINYF 1.17549435e-38f

__device__ __forceinline__ void threefry2x32_01(unsigned x0, unsigned x1,
                                                unsigned& o0, unsigned& o1) {
    const unsigned ks0 = 0u, ks1 = 1u, ks2 = 0x1BD11BDBu; // 0x1BD11BDA ^ 0 ^ 1
    x0 += ks0; x1 += ks1;
#define TF_R(r) { x0 += x1; x1 = (x1 << (r)) | (x1 >> (32 - (r))); x1 ^= x0; }
    TF_R(13) TF_R(15) TF_R(26) TF_R(6)
    x0 += ks1; x1 += ks2 + 1u;
    TF_R(17) TF_R(29) TF_R(16) TF_R(24)
    x0 += ks2; x1 += ks0 + 2u;
    TF_R(13) TF_R(15) TF_R(26) TF_R(6)
    x0 += ks0; x1 += ks1 + 3u;
    TF_R(17) TF_R(29) TF_R(16) TF_R(24)
    x0 += ks1; x1 += ks2 + 4u;
    TF_R(13) TF_R(15) TF_R(26) TF_R(6)
    x0 += ks2; x1 += ks0 + 5u;
#undef TF_R
    o0 = x0; o1 = x1;
}

// jax_threefry_partitionable=True: counter (hi=0, lo=n), out = o0 ^ o1.
__device__ __forceinline__ unsigned jax_random_bits(unsigned n) {
    unsigned o0, o1;
    threefry2x32_01(0u, n, o0, o1);
    return o0 ^ o1;
}

__device__ __forceinline__ bool bad_val(float v) {
    return ((__float_as_uint(v) & 0x7F800000u) == 0x7F800000u) || (v < 0.0f);
}

// ---------------- Kernel A: channel max + tiny middle -> gate[B,64] ----------
__global__ __launch_bounds__(NT_A) void sa_gate_kernel(
    const float* __restrict__ x,
    const float* __restrict__ w11,
    const float* __restrict__ w5,
    const float* __restrict__ b5,
    const float* __restrict__ w6,
    const float* __restrict__ b6,
    float* __restrict__ gate_out)
{
    const int b = blockIdx.x;
    const int t = threadIdx.x;

    const float4* __restrict__ xb = (const float4*)x + (size_t)b * F4_PER_BATCH;

    __shared__ float4 red[8 * 16];  // per-wave partial max, 16 float4 groups
    __shared__ float sm[64];
    __shared__ float sa16[16];
    __shared__ float sb16[16];
    __shared__ float so2[64];
    __shared__ float shid[4 * 64];

    // Contiguous streaming read: wave reads 1 KB per instruction.
    // Thread t covers float4 flat indices t + 512*i  ->  hw4 group = t&15 fixed.
    float4 pm = make_float4(-INFINITY, -INFINITY, -INFINITY, -INFINITY);
#pragma unroll 16
    for (int i = 0; i < 32; ++i) {
        float4 v = xb[t + NT_A * i];
        pm.x = fmaxf(pm.x, v.x); pm.y = fmaxf(pm.y, v.y);
        pm.z = fmaxf(pm.z, v.z); pm.w = fmaxf(pm.w, v.w);
    }
    // Wave-level reduce over the 4 c-slices within this wave (lanes xor 16, 32).
#pragma unroll
    for (int off = 16; off <= 32; off <<= 1) {
        pm.x = fmaxf(pm.x, __shfl_xor(pm.x, off, 64));
        pm.y = fmaxf(pm.y, __shfl_xor(pm.y, off, 64));
        pm.z = fmaxf(pm.z, __shfl_xor(pm.z, off, 64));
        pm.w = fmaxf(pm.w, __shfl_xor(pm.w, off, 64));
    }
    const int wv = t >> 6, lane = t & 63;
    if (lane < 16) red[wv * 16 + lane] = pm;
    __syncthreads();
    if (t >= 64) return;  // waves 1-7 done; wave 0 runs the middle barrier-free

    // Final reduce across the 8 wave partials (lanes 0..15).
    if (t < 16) {
        float4 a = red[t];
#pragma unroll
        for (int w = 1; w < 8; ++w) {
            float4 o = red[w * 16 + t];
            a.x = fmaxf(a.x, o.x); a.y = fmaxf(a.y, o.y);
            a.z = fmaxf(a.z, o.z); a.w = fmaxf(a.w, o.w);
        }
        sm[t * 4 + 0] = a.x; sm[t * 4 + 1] = a.y;
        sm[t * 4 + 2] = a.z; sm[t * 4 + 3] = a.w;
    }
    __builtin_amdgcn_wave_barrier();

    // Windows: categorical (exact JAX gumbel) + max + mean pooling. Lanes 0..15.
    if (t < 16) {
        int h2 = t >> 2, w2 = t & 3;
        float win[4], winc[4], sg[4];
#pragma unroll
        for (int j = 0; j < 4; ++j) {
            int hh = 2 * h2 + (j >> 1), ww = 2 * w2 + (j & 1);
            float v = sm[hh * 8 + ww];
            win[j] = v;
            winc[j] = bad_val(v) ? EPSV : v;
            unsigned n = (unsigned)(b * 64 + t * 4 + j);
            unsigned bits = jax_random_bits(n);
            float f = __uint_as_float(0x3F800000u | (bits >> 9)) - 1.0f;
            float u = fmaxf(TINYF, f + TINYF);
            sg[j] = -logf(-logf(u));
        }
        int idx = 0;
        float best = winc[0] + sg[0];
#pragma unroll
        for (int j = 1; j < 4; ++j) {
            float s = winc[j] + sg[j];
            if (s > best) { best = s; idx = j; }
        }
        float mo2 = winc[idx];
        float mo3 = fmaxf(fmaxf(win[0], win[1]), fmaxf(win[2], win[3]));
        float ssum = ((win[0] + win[1]) + win[2]) + win[3];
        float ao4 = ssum * 0.25f;
        sa16[t] = 0.1f * mo2 + 0.6f * mo3 + 0.3f * ao4;
    }
    __builtin_amdgcn_wave_barrier();

    // 3x3 conv (1->1, SAME, no bias) on 4x4. Lanes 0..15.
    if (t < 16) {
        int i = t >> 2, j = t & 3;
        float acc = 0.0f;
#pragma unroll
        for (int dy = -1; dy <= 1; ++dy) {
            int yy = i + dy;
            if (yy < 0 || yy > 3) continue;
#pragma unroll
            for (int dx = -1; dx <= 1; ++dx) {
                int xx = j + dx;
                if (xx < 0 || xx > 3) continue;
                acc += sa16[yy * 4 + xx] * w11[(dy + 1) * 3 + (dx + 1)];
            }
        }
        sb16[t] = acc;
    }
    __builtin_amdgcn_wave_barrier();

    // Bilinear resize 4x4 -> 8x8 (align_corners=False). All 64 lanes.
    {
        int y = t >> 3, xx2 = t & 7;
        float sy = (y + 0.5f) * 0.5f - 0.5f;
        float sx = (xx2 + 0.5f) * 0.5f - 0.5f;
        float fy = fminf(fmaxf(sy, 0.0f), 3.0f);
        float fx = fminf(fmaxf(sx, 0.0f), 3.0f);
        int iy0 = (int)floorf(fy); int iy1 = min(iy0 + 1, 3); float ry = fy - (float)iy0;
        int ix0 = (int)floorf(fx); int ix1 = min(ix0 + 1, 3); float rx = fx - (float)ix0;
        float v00 = sb16[iy0 * 4 + ix0], v01 = sb16[iy0 * 4 + ix1];
        float v10 = sb16[iy1 * 4 + ix0], v11 = sb16[iy1 * 4 + ix1];
        float top = v00 * (1.0f - rx) + v01 * rx;
        float bot = v10 * (1.0f - rx) + v11 * rx;
        so2[t] = top * (1.0f - ry) + bot * ry;
    }
    __builtin_amdgcn_wave_barrier();

    // conv5: [2->4] 3x3 SAME + bias + relu on 8x8 (ch0 = m, ch1 = out2).
    {
        int y = t >> 3, x2 = t & 7;
        float a0 = b5[0], a1 = b5[1], a2 = b5[2], a3 = b5[3];
#pragma unroll
        for (int dy = -1; dy <= 1; ++dy) {
            int yy = y + dy;
            if (yy < 0 || yy > 7) continue;
#pragma unroll
            for (int dx = -1; dx <= 1; ++dx) {
                int xx = x2 + dx;
                if (xx < 0 || xx > 7) continue;
                float i0 = sm[yy * 8 + xx];
                float i1 = so2[yy * 8 + xx];
                int kk = (dy + 1) * 3 + (dx + 1);
                a0 += i0 * w5[0 * 18 + kk] + i1 * w5[0 * 18 + 9 + kk];
                a1 += i0 * w5[1 * 18 + kk] + i1 * w5[1 * 18 + 9 + kk];
                a2 += i0 * w5[2 * 18 + kk] + i1 * w5[2 * 18 + 9 + kk];
                a3 += i0 * w5[3 * 18 + kk] + i1 * w5[3 * 18 + 9 + kk];
            }
        }
        shid[0 * 64 + t] = fmaxf(a0, 0.0f);
        shid[1 * 64 + t] = fmaxf(a1, 0.0f);
        shid[2 * 64 + t] = fmaxf(a2, 0.0f);
        shid[3 * 64 + t] = fmaxf(a3, 0.0f);
    }
    __builtin_amdgcn_wave_barrier();

    // conv6: [4->1] 3x3 SAME + bias + sigmoid -> gate.
    {
        int y = t >> 3, x2 = t & 7;
        float acc = b6[0];
#pragma unroll
        for (int dy = -1; dy <= 1; ++dy) {
            int yy = y + dy;
            if (yy < 0 || yy > 7) continue;
#pragma unroll
            for (int dx = -1; dx <= 1; ++dx) {
                int xx = x2 + dx;
                if (xx < 0 || xx > 7) continue;
                int kk = (dy + 1) * 3 + (dx + 1);
                int p = yy * 8 + xx;
                acc += shid[0 * 64 + p] * w6[0 + kk]
                     + shid[1 * 64 + p] * w6[9 + kk]
                     + shid[2 * 64 + p] * w6[18 + kk]
                     + shid[3 * 64 + p] * w6[27 + kk];
            }
        }
        gate_out[b * 64 + t] = 1.0f / (1.0f + expf(-acc));
    }
}

// ---------------- Kernel B: out = relu(x * gate), pure stream ----------------
// 4 blocks per batch; each block streams a contiguous 64 KB quarter-batch.
// Thread's hw4 group is fixed -> gate loaded exactly once per thread.
__global__ __launch_bounds__(NT_B) void sa_apply_kernel(
    const float* __restrict__ x,
    const float* __restrict__ gate,
    float* __restrict__ out)
{
    const int bid = blockIdx.x;
    const int t = threadIdx.x;
    const int b = bid >> 2;
    const size_t base = (size_t)bid * 4096;  // float4 units

    const float4* __restrict__ x4 = (const float4*)x;
    float4* __restrict__ o4 = (float4*)out;

    const float4 gv = ((const float4*)(gate + b * 64))[t & 15];

#pragma unroll 8
    for (int i = 0; i < 16; ++i) {
        size_t idx = base + t + NT_B * i;
        float4 v = x4[idx];
        float4 o;
        o.x = fmaxf(v.x * gv.x, 0.0f);
        o.y = fmaxf(v.y * gv.y, 0.0f);
        o.z = fmaxf(v.z * gv.z, 0.0f);
        o.w = fmaxf(v.w * gv.w, 0.0f);
        o4[idx] = o;
    }
}

extern "C" void kernel_launch(void* const* d_in, const int* in_sizes, int n_in,
                              void* d_out, int out_size, void* d_ws, size_t ws_size,
                              hipStream_t stream) {
    const float* x   = (const float*)d_in[0];
    const float* w11 = (const float*)d_in[1];
    const float* w5  = (const float*)d_in[2];
    const float* b5  = (const float*)d_in[3];
    const float* w6  = (const float*)d_in[4];
    const float* b6  = (const float*)d_in[5];
    float* out  = (float*)d_out;
    float* gate = (float*)d_ws;  // B*64 floats = 128 KB

    int B = in_sizes[0] / (C_DIM * HW);  // 512
    sa_gate_kernel<<<dim3(B), dim3(NT_A), 0, stream>>>(x, w11, w5, b5, w6, b6, gate);
    sa_apply_kernel<<<dim3(B * 4), dim3(NT_B), 0, stream>>>(x, gate, out);
}